// Round 1
// baseline (611.149 us; speedup 1.0000x reference)
//
#include <hip/hip_runtime.h>
#include <math.h>

// ---------------------------------------------------------------------------
// VariableTransformerBlock on MI355X (gfx950)
// B=2, S=2048, E=1024, H=16, D=64, F=4096. fp32 in/out, bf16 MFMA internally.
// ---------------------------------------------------------------------------

typedef __attribute__((ext_vector_type(8))) short short8;   // 8 x bf16 (4 VGPRs)
typedef __attribute__((ext_vector_type(4))) float f32x4;    // MFMA accumulator

__device__ __forceinline__ unsigned short f2bf(float f) {
  unsigned int u = __float_as_uint(f);
  u += 0x7fffu + ((u >> 16) & 1u);   // round-to-nearest-even
  return (unsigned short)(u >> 16);
}

// ---------------------------------------------------------------------------
// fp32 -> bf16 conversion (weights / none else). n4 = number of float4 groups.
// ---------------------------------------------------------------------------
__global__ __launch_bounds__(256) void conv_f32_bf16(const float* __restrict__ in,
                                                     unsigned short* __restrict__ out,
                                                     int n4) {
  int i = blockIdx.x * 256 + threadIdx.x;
  if (i < n4) {
    float4 v = ((const float4*)in)[i];
    ushort4 u;
    u.x = f2bf(v.x); u.y = f2bf(v.y); u.z = f2bf(v.z); u.w = f2bf(v.w);
    ((ushort4*)out)[i] = u;
  }
}

// ---------------------------------------------------------------------------
// LayerNorm: one block per row of 1024 fp32, writes bf16.
// ---------------------------------------------------------------------------
__global__ __launch_bounds__(256) void ln_kernel(const float* __restrict__ x,
                                                 const float* __restrict__ g,
                                                 const float* __restrict__ b,
                                                 unsigned short* __restrict__ out) {
  int row = blockIdx.x;
  int t = threadIdx.x;
  const float4* x4 = (const float4*)(x + (size_t)row * 1024);
  float4 v = x4[t];
  float s1 = v.x + v.y + v.z + v.w;
  float s2 = v.x * v.x + v.y * v.y + v.z * v.z + v.w * v.w;
  for (int off = 1; off < 64; off <<= 1) {
    s1 += __shfl_xor(s1, off, 64);
    s2 += __shfl_xor(s2, off, 64);
  }
  __shared__ float r1[4], r2[4];
  int w = t >> 6, lane = t & 63;
  if (lane == 0) { r1[w] = s1; r2[w] = s2; }
  __syncthreads();
  s1 = r1[0] + r1[1] + r1[2] + r1[3];
  s2 = r2[0] + r2[1] + r2[2] + r2[3];
  float mu = s1 * (1.0f / 1024.0f);
  float var = s2 * (1.0f / 1024.0f) - mu * mu;
  float rstd = rsqrtf(var + 1e-5f);
  int c = t * 4;
  float4 gv = ((const float4*)g)[t];
  float4 bv = ((const float4*)b)[t];
  unsigned short* o = out + (size_t)row * 1024 + c;
  o[0] = f2bf((v.x - mu) * rstd * gv.x + bv.x);
  o[1] = f2bf((v.y - mu) * rstd * gv.y + bv.y);
  o[2] = f2bf((v.z - mu) * rstd * gv.z + bv.z);
  o[3] = f2bf((v.w - mu) * rstd * gv.w + bv.w);
}

// ---------------------------------------------------------------------------
// GEMM: C[M,N] = A[M,K](bf16) @ W[N,K](bf16)^T + bias.
// 128x128 block tile, 4 waves in 2x2, each wave 64x64 (4x4 of 16x16 MFMA).
// MODE 0: QKV epilogue -> scatter bf16 into q(B,H,S,D), k(B,H,S,D), vT(B,H,D,S)
// MODE 1: fp32 out = acc + bias + resid
// MODE 2: bf16 out = gelu_exact(acc + bias)
// ---------------------------------------------------------------------------
#define LDK 40  // 32 + 8 pad (keeps 16B alignment, kills bank conflicts)

template <int MODE>
__global__ __launch_bounds__(256) void gemm_bt(
    const unsigned short* __restrict__ A, const unsigned short* __restrict__ W,
    const float* __restrict__ bias, int M, int N, int K,
    const float* __restrict__ resid, float* __restrict__ out_f32,
    unsigned short* __restrict__ out_bf16,
    unsigned short* __restrict__ qb, unsigned short* __restrict__ kb,
    unsigned short* __restrict__ vtb) {
  __shared__ unsigned short As[128 * LDK];
  __shared__ unsigned short Ws[128 * LDK];
  int tid = threadIdx.x;
  int w = tid >> 6, lane = tid & 63, quad = lane >> 4, l16 = lane & 15;
  int wrow = w >> 1, wcol = w & 1;
  int m0 = blockIdx.y * 128, n0 = blockIdx.x * 128;

  f32x4 acc[4][4] = {};

  for (int k0 = 0; k0 < K; k0 += 32) {
    __syncthreads();
    for (int i = 0; i < 2; i++) {
      int idx = tid + i * 256;
      int row = idx >> 2, seg = idx & 3;
      short8 av = *(const short8*)(A + (size_t)(m0 + row) * K + k0 + seg * 8);
      *(short8*)(As + row * LDK + seg * 8) = av;
      short8 wv = *(const short8*)(W + (size_t)(n0 + row) * K + k0 + seg * 8);
      *(short8*)(Ws + row * LDK + seg * 8) = wv;
    }
    __syncthreads();
    short8 af[4], bf[4];
    for (int i = 0; i < 4; i++)
      af[i] = *(const short8*)(As + (wrow * 64 + i * 16 + l16) * LDK + quad * 8);
    for (int j = 0; j < 4; j++)
      bf[j] = *(const short8*)(Ws + (wcol * 64 + j * 16 + l16) * LDK + quad * 8);
    for (int i = 0; i < 4; i++)
      for (int j = 0; j < 4; j++)
        acc[i][j] = __builtin_amdgcn_mfma_f32_16x16x32_bf16(af[i], bf[j], acc[i][j], 0, 0, 0);
  }

  for (int j = 0; j < 4; j++) {
    int col = n0 + wcol * 64 + j * 16 + l16;
    float bv = bias[col];
    for (int i = 0; i < 4; i++) {
      int row0 = m0 + wrow * 64 + i * 16 + quad * 4;
      for (int r = 0; r < 4; r++) {
        int row = row0 + r;
        float v = acc[i][j][r] + bv;
        if (MODE == 0) {
          int which = col >> 10;
          int rr2 = col & 1023;
          int hh = rr2 >> 6, d = rr2 & 63;
          int bb = row >> 11, s = row & 2047;
          int bh = bb * 16 + hh;
          unsigned short bv16 = f2bf(v);
          if (which == 0)      qb[((size_t)bh * 2048 + s) * 64 + d] = bv16;
          else if (which == 1) kb[((size_t)bh * 2048 + s) * 64 + d] = bv16;
          else                 vtb[((size_t)bh * 64 + d) * 2048 + s] = bv16;
        } else if (MODE == 1) {
          out_f32[(size_t)row * N + col] = v + resid[(size_t)row * N + col];
        } else {
          float gval = 0.5f * v * (1.0f + erff(v * 0.70710678118f));
          out_bf16[(size_t)row * N + col] = f2bf(gval);
        }
      }
    }
  }
}

// ---------------------------------------------------------------------------
// Flash-style attention. Grid: (S/32, B*H). Block 256 (4 waves).
// Q-tile = 32 rows, key chunk = 256. Wave w owns d-slice [w*16, w*16+16) of O
// and keys [w*64, w*64+64) of each score chunk, and softmax rows [w*8, w*8+8).
// q,k in (B,H,S,D); v transposed as (B,H,D,S); all bf16. o written bf16 (B,S,E).
// ---------------------------------------------------------------------------
__global__ __launch_bounds__(256) void attn_kernel(const unsigned short* __restrict__ qb,
                                                   const unsigned short* __restrict__ kb,
                                                   const unsigned short* __restrict__ vtb,
                                                   unsigned short* __restrict__ ob) {
  __shared__ float sc[32 * 260];            // fp32 scores, pad 260 (2-way, free)
  __shared__ unsigned short pb[32 * 264];   // bf16 probabilities, pad 264
  __shared__ float alpha_s[32];
  __shared__ float l_s[32];

  int tid = threadIdx.x;
  int w = tid >> 6, lane = tid & 63, quad = lane >> 4, l16 = lane & 15;
  int bh = blockIdx.y;
  int q0 = blockIdx.x * 32;

  const unsigned short* qbase = qb + ((size_t)bh * 2048 + q0) * 64;
  const unsigned short* kbase = kb + (size_t)bh * 2048 * 64;
  const unsigned short* vbase = vtb + (size_t)bh * 64 * 2048 + (size_t)(w * 16 + l16) * 2048 + quad * 8;

  short8 qf[2][2];
  for (int im = 0; im < 2; im++)
    for (int ks = 0; ks < 2; ks++)
      qf[im][ks] = *(const short8*)(qbase + (im * 16 + l16) * 64 + ks * 32 + quad * 8);

  float m_run[8], l_run[8];
  for (int i = 0; i < 8; i++) { m_run[i] = -1e30f; l_run[i] = 0.0f; }
  f32x4 oacc[2] = {};
  const float scale = 0.125f;  // 1/sqrt(64)

  for (int c0 = 0; c0 < 2048; c0 += 256) {
    // ---- QK^T for this chunk
    for (int t = 0; t < 4; t++) {
      int key0 = c0 + w * 64 + t * 16;
      short8 kf0 = *(const short8*)(kbase + (size_t)(key0 + l16) * 64 + quad * 8);
      short8 kf1 = *(const short8*)(kbase + (size_t)(key0 + l16) * 64 + 32 + quad * 8);
      for (int im = 0; im < 2; im++) {
        f32x4 s4 = {0.0f, 0.0f, 0.0f, 0.0f};
        s4 = __builtin_amdgcn_mfma_f32_16x16x32_bf16(qf[im][0], kf0, s4, 0, 0, 0);
        s4 = __builtin_amdgcn_mfma_f32_16x16x32_bf16(qf[im][1], kf1, s4, 0, 0, 0);
        int coll = w * 64 + t * 16 + l16;
        for (int r = 0; r < 4; r++)
          sc[(im * 16 + quad * 4 + r) * 260 + coll] = s4[r] * scale;
      }
    }
    __syncthreads();
    // ---- online softmax, wave handles rows w*8 .. w*8+7
    for (int rr = 0; rr < 8; rr++) {
      int row = w * 8 + rr;
      float v0 = sc[row * 260 + lane];
      float v1 = sc[row * 260 + 64 + lane];
      float v2 = sc[row * 260 + 128 + lane];
      float v3 = sc[row * 260 + 192 + lane];
      float mx = fmaxf(fmaxf(v0, v1), fmaxf(v2, v3));
      for (int off = 1; off < 64; off <<= 1) mx = fmaxf(mx, __shfl_xor(mx, off, 64));
      float mnew = fmaxf(m_run[rr], mx);
      float al = __expf(m_run[rr] - mnew);
      float p0 = __expf(v0 - mnew), p1 = __expf(v1 - mnew);
      float p2 = __expf(v2 - mnew), p3 = __expf(v3 - mnew);
      pb[row * 264 + lane] = f2bf(p0);
      pb[row * 264 + 64 + lane] = f2bf(p1);
      pb[row * 264 + 128 + lane] = f2bf(p2);
      pb[row * 264 + 192 + lane] = f2bf(p3);
      float s = p0 + p1 + p2 + p3;
      for (int off = 1; off < 64; off <<= 1) s += __shfl_xor(s, off, 64);
      l_run[rr] = l_run[rr] * al + s;
      m_run[rr] = mnew;
      if (lane == 0) alpha_s[row] = al;
    }
    __syncthreads();
    // ---- rescale O, then PV accumulate over this chunk
    for (int im = 0; im < 2; im++)
      for (int r = 0; r < 4; r++)
        oacc[im][r] *= alpha_s[im * 16 + quad * 4 + r];
    for (int ks = 0; ks < 8; ks++) {
      short8 bfv = *(const short8*)(vbase + c0 + ks * 32);
      for (int im = 0; im < 2; im++) {
        short8 afv = *(const short8*)(pb + (im * 16 + l16) * 264 + ks * 32 + quad * 8);
        oacc[im] = __builtin_amdgcn_mfma_f32_16x16x32_bf16(afv, bfv, oacc[im], 0, 0, 0);
      }
    }
    __syncthreads();  // before next chunk overwrites sc/pb
  }

  if (lane == 0)
    for (int rr = 0; rr < 8; rr++) l_s[w * 8 + rr] = l_run[rr];
  __syncthreads();

  int bb = bh >> 4, hh = bh & 15;
  for (int im = 0; im < 2; im++) {
    for (int r = 0; r < 4; r++) {
      int row = im * 16 + quad * 4 + r;
      float val = oacc[im][r] / l_s[row];
      size_t tok = (size_t)bb * 2048 + q0 + row;
      ob[tok * 1024 + hh * 64 + w * 16 + l16] = f2bf(val);
    }
  }
}

// ---------------------------------------------------------------------------
// Launch
// ---------------------------------------------------------------------------
extern "C" void kernel_launch(void* const* d_in, const int* in_sizes, int n_in,
                              void* d_out, int out_size, void* d_ws, size_t ws_size,
                              hipStream_t stream) {
  (void)in_sizes; (void)n_in; (void)out_size; (void)ws_size;
  const float* x     = (const float*)d_in[0];
  const float* qkv_w = (const float*)d_in[1];
  const float* qkv_b = (const float*)d_in[2];
  const float* out_w = (const float*)d_in[3];
  const float* out_b = (const float*)d_in[4];
  const float* ff1_w = (const float*)d_in[5];
  const float* ff1_b = (const float*)d_in[6];
  const float* ff2_w = (const float*)d_in[7];
  const float* ff2_b = (const float*)d_in[8];
  const float* ln1_g = (const float*)d_in[9];
  const float* ln1_b = (const float*)d_in[10];
  const float* ln2_g = (const float*)d_in[11];
  const float* ln2_b = (const float*)d_in[12];
  float* out = (float*)d_out;
  char* ws = (char*)d_ws;

  const int M = 4096;  // B*S

  // ws layout (bytes)
  unsigned short* WQ = (unsigned short*)(ws + 0);           //  6,291,456
  unsigned short* WO = (unsigned short*)(ws + 6291456);     //  2,097,152
  unsigned short* W1 = (unsigned short*)(ws + 8388608);     //  8,388,608
  unsigned short* W2 = (unsigned short*)(ws + 16777216);    //  8,388,608
  unsigned short* Hb = (unsigned short*)(ws + 25165824);    //  8,388,608
  unsigned short* Qb = (unsigned short*)(ws + 33554432);    //  8,388,608
  unsigned short* Kb = (unsigned short*)(ws + 41943040);    //  8,388,608
  unsigned short* VT = (unsigned short*)(ws + 50331648);    //  8,388,608
  unsigned short* Ob = (unsigned short*)(ws + 58720256);    //  8,388,608
  float*          X1 = (float*)(ws + 67108864);             // 16,777,216
  unsigned short* Gb = (unsigned short*)(ws + 33554432);    // 33,554,432 (reuses Q/K/VT/O after out-proj)
  // total ws footprint: 83,886,080 bytes (80 MB)

  // 1. weight conversions fp32 -> bf16
  conv_f32_bf16<<<3072, 256, 0, stream>>>(qkv_w, WQ, 786432);
  conv_f32_bf16<<<1024, 256, 0, stream>>>(out_w, WO, 262144);
  conv_f32_bf16<<<4096, 256, 0, stream>>>(ff1_w, W1, 1048576);
  conv_f32_bf16<<<4096, 256, 0, stream>>>(ff2_w, W2, 1048576);

  // 2. LN1: x -> Hb (bf16)
  ln_kernel<<<4096, 256, 0, stream>>>(x, ln1_g, ln1_b, Hb);

  // 3. QKV GEMM: (4096x1024)@(3072x1024)^T -> scatter q/k/vT
  gemm_bt<0><<<dim3(24, 32), 256, 0, stream>>>(Hb, WQ, qkv_b, M, 3072, 1024,
                                               nullptr, nullptr, nullptr, Qb, Kb, VT);

  // 4. attention -> Ob bf16 (B,S,E)
  attn_kernel<<<dim3(64, 32), 256, 0, stream>>>(Qb, Kb, VT, Ob);

  // 5. out-proj + residual: X1 = x + Ob@WO^T + out_b  (fp32)
  gemm_bt<1><<<dim3(8, 32), 256, 0, stream>>>(Ob, WO, out_b, M, 1024, 1024,
                                              x, X1, nullptr, nullptr, nullptr, nullptr);

  // 6. LN2: X1 -> Hb (bf16)
  ln_kernel<<<4096, 256, 0, stream>>>(X1, ln2_g, ln2_b, Hb);

  // 7. FF1 + exact GELU: Gb = gelu(Hb@W1^T + ff1_b) bf16 (4096x4096)
  gemm_bt<2><<<dim3(32, 32), 256, 0, stream>>>(Hb, W1, ff1_b, M, 4096, 1024,
                                               nullptr, nullptr, Gb, nullptr, nullptr, nullptr);

  // 8. FF2 + residual: out = X1 + Gb@W2^T + ff2_b (fp32)
  gemm_bt<1><<<dim3(8, 32), 256, 0, stream>>>(Gb, W2, ff2_b, M, 1024, 4096,
                                              X1, out, nullptr, nullptr, nullptr, nullptr);
}